// Round 4
// baseline (1054.829 us; speedup 1.0000x reference)
//
#include <hip/hip_runtime.h>

// MLA forward. f32 in/out storage; internal bf16 MFMA, f32 accum.
// B=2 S=1024 H=32 HID=4096 QL=1536 KVL=512 ROPE=64 V=128 D=576
// Round 8: fix gemm256 staging to lane-linear LDS dests (global_load_lds
// writes base+lane*16B; round-7's 32B/lane spacing scrambled the K-tiles).
// Each stage instruction now covers one contiguous 8192B span. Sync schedule
// (counted vmcnt(4), 2-phase barriers, omega lgkm drain) unchanged.

typedef __attribute__((ext_vector_type(8))) short s16x8;
typedef __attribute__((ext_vector_type(4))) float f32x4;

__device__ __forceinline__ float bf2f(unsigned short u) {
  union { unsigned int i; float f; } v; v.i = ((unsigned int)u) << 16; return v.f;
}
__device__ __forceinline__ unsigned short f2bf(float f) {
  union { float f; unsigned int i; } v; v.f = f;
  unsigned int x = v.i;
  x += 0x7fffu + ((x >> 16) & 1u);   // RNE
  return (unsigned short)(x >> 16);
}

__device__ __forceinline__ void async16(const unsigned short* g, unsigned short* l) {
  __builtin_amdgcn_global_load_lds(
      (const __attribute__((address_space(1))) unsigned int*)g,
      (__attribute__((address_space(3))) unsigned int*)l, 16, 0, 0);
}

// ---------------------------------------------------------------------------
// f32 -> bf16 straight convert, 8 elems/thread, exact grid
// ---------------------------------------------------------------------------
__global__ __launch_bounds__(256) void conv_bf16(
    const float* __restrict__ s, unsigned short* __restrict__ d)
{
  const long long i = ((long long)blockIdx.x * 256 + threadIdx.x) * 8;
  float4 a = *(const float4*)(s + i);
  float4 b = *(const float4*)(s + i + 4);
  union { uint4 v; unsigned short u[8]; } o;
  o.u[0] = f2bf(a.x); o.u[1] = f2bf(a.y); o.u[2] = f2bf(a.z); o.u[3] = f2bf(a.w);
  o.u[4] = f2bf(b.x); o.u[5] = f2bf(b.y); o.u[6] = f2bf(b.z); o.u[7] = f2bf(b.w);
  *(uint4*)(d + i) = o.v;
}

// ---------------------------------------------------------------------------
// f32 [R][C] -> bf16 [Cp][R] transpose+convert. 32x32 tiles; tiles with
// c0 >= C write zeros (N padding). R%32==0, C%32==0, C%4==0.
// ---------------------------------------------------------------------------
__global__ __launch_bounds__(256) void transpose_w(
    const float* __restrict__ src, unsigned short* __restrict__ dst,
    int R, int C, long long sS, long long sD)
{
  __shared__ unsigned short tile[32][36];
  src += (long long)blockIdx.z * sS;
  dst += (long long)blockIdx.z * sD;
  const int c0 = blockIdx.x * 32, r0 = blockIdx.y * 32;
  const int tid = threadIdx.x;
  const int rr = tid >> 3, cc4 = (tid & 7) * 4;
  if (c0 < C) {
    float4 v = *(const float4*)(src + (long long)(r0 + rr) * C + c0 + cc4);
    tile[cc4 + 0][rr] = f2bf(v.x); tile[cc4 + 1][rr] = f2bf(v.y);
    tile[cc4 + 2][rr] = f2bf(v.z); tile[cc4 + 3][rr] = f2bf(v.w);
  } else {
#pragma unroll
    for (int j = 0; j < 4; ++j) tile[cc4 + j][rr] = 0;
  }
  __syncthreads();
  const int cr = tid >> 3, rc4 = (tid & 7) * 4;
  union { uint2 v; unsigned short u[4]; } o;
#pragma unroll
  for (int j = 0; j < 4; ++j) o.u[j] = tile[cr][rc4 + j];
  *(uint2*)(dst + (long long)(c0 + cr) * R + r0 + rc4) = o.v;
}

// ---------------------------------------------------------------------------
// m97-style GEMM: C[M,N] = A[M,K] * Bt[N,K]^T. A,Bt bf16 row-major.
// 128x128 block tile, BK=32, 4 waves each 64x64 (4x4 of mfma 16x16x32).
// ---------------------------------------------------------------------------
template<int ODT>
__global__ __launch_bounds__(256) void gemm128(
    const unsigned short* __restrict__ A, const unsigned short* __restrict__ Bt,
    void* __restrict__ Cv, int K, int lda, int ldb, int ldc, int batH,
    long long sAb, long long sAh, long long sBb, long long sBh,
    long long sCb, long long sCh)
{
  const int z = blockIdx.z;
  const int bz = z / batH, hz = z % batH;
  A  += (long long)bz * sAb + (long long)hz * sAh;
  Bt += (long long)bz * sBb + (long long)hz * sBh;
  const long long co = (long long)bz * sCb + (long long)hz * sCh;

  __shared__ __align__(16) unsigned short As[128 * 32];
  __shared__ __align__(16) unsigned short Bs[128 * 32];

  const int tid = threadIdx.x, w = tid >> 6, lane = tid & 63;
  const int quad = lane >> 4, ml = lane & 15;
  const int wm = (w >> 1) * 64, wn = (w & 1) * 64;
  const int m0 = blockIdx.y * 128, n0 = blockIdx.x * 128;

  const int r0 = tid >> 2, k8 = (tid & 3) * 8;
  const unsigned short* Ag0 = A  + (long long)(m0 + r0)      * lda + k8;
  const unsigned short* Ag1 = A  + (long long)(m0 + r0 + 64) * lda + k8;
  const unsigned short* Bg0 = Bt + (long long)(n0 + r0)      * ldb + k8;
  const unsigned short* Bg1 = Bt + (long long)(n0 + r0 + 64) * ldb + k8;
  unsigned short* la0 = &As[tid * 8];
  unsigned short* la1 = &As[(tid + 256) * 8];
  unsigned short* lb0 = &Bs[tid * 8];
  unsigned short* lb1 = &Bs[(tid + 256) * 8];

  f32x4 acc[4][4] = {};

  for (int k0 = 0; k0 < K; k0 += 32) {
    __syncthreads();                  // LDS reads of prev iter done
    async16(Ag0 + k0, la0);
    async16(Ag1 + k0, la1);
    async16(Bg0 + k0, lb0);
    async16(Bg1 + k0, lb1);
    __syncthreads();                  // drains vmcnt before barrier

    s16x8 af[4], bf[4];
#pragma unroll
    for (int mi = 0; mi < 4; ++mi)
      af[mi] = *(const s16x8*)(&As[(wm + mi * 16 + ml) * 32 + quad * 8]);
#pragma unroll
    for (int ni = 0; ni < 4; ++ni)
      bf[ni] = *(const s16x8*)(&Bs[(wn + ni * 16 + ml) * 32 + quad * 8]);
#pragma unroll
    for (int mi = 0; mi < 4; ++mi)
#pragma unroll
      for (int ni = 0; ni < 4; ++ni)
        acc[mi][ni] = __builtin_amdgcn_mfma_f32_16x16x32_bf16(af[mi], bf[ni], acc[mi][ni], 0, 0, 0);
  }

#pragma unroll
  for (int mi = 0; mi < 4; ++mi)
#pragma unroll
    for (int ni = 0; ni < 4; ++ni)
#pragma unroll
      for (int r = 0; r < 4; ++r) {
        const int row = m0 + wm + mi * 16 + quad * 4 + r;
        const int col = n0 + wn + ni * 16 + ml;
        if (ODT)
          ((unsigned short*)Cv)[co + (long long)row * ldc + col] = f2bf(acc[mi][ni][r]);
        else
          ((float*)Cv)[co + (long long)row * ldc + col] = acc[mi][ni][r];
      }
}

// ---------------------------------------------------------------------------
// gemm256: C[M,N] = A[M,K] * Bt[N,K]^T, BM=128 BN=256 BK=64, 512 thr / 8 waves
// (wr=w>>2 in M, wc=w&3 in N; per-wave 64x64 = 4x4 frags). LDS double-buffered
// (As 2x[128][64], Bs 2x[256][64], 96 KB). Staging: each async16 instruction
// covers one contiguous 8192B span, lane-linear dest (tid*16B); instruction j
// = rows [64j,64j+64), thread row = j*64 + (tid>>3), chunk = tid&7, global
// source column pre-swizzled (tid&7)^(row&7). Read side applies the same XOR.
// Per K-tile: 2 phases; counted vmcnt(4) at tile top (never 0 in steady
// state). M%128==0, N%256==0, K%64==0.
// ---------------------------------------------------------------------------
template<int ODT>
__global__ __launch_bounds__(512) void gemm256(
    const unsigned short* __restrict__ A, const unsigned short* __restrict__ Bt,
    void* __restrict__ Cv, int K, int lda, int ldb, int ldc, int batH,
    long long sAb, long long sAh, long long sBb, long long sBh,
    long long sCb, long long sCh)
{
  __shared__ __align__(16) unsigned short As[2 * 128 * 64];   // 32768 B
  __shared__ __align__(16) unsigned short Bs[2 * 256 * 64];   // 65536 B

  const int z = blockIdx.z;
  const int bz = z / batH, hz = z % batH;
  A  += (long long)bz * sAb + (long long)hz * sAh;
  Bt += (long long)bz * sBb + (long long)hz * sBh;
  const long long co = (long long)bz * sCb + (long long)hz * sCh;

  const int tid = threadIdx.x, w = tid >> 6, lane = tid & 63;
  const int quad = lane >> 4, ml = lane & 15;
  const int wr = w >> 2, wc = w & 3;
  const int e3 = ml & 7;
  const int m0 = blockIdx.y * 128, n0 = blockIdx.x * 256;

  // staging addresses (lane-linear dest: thread's row = j*64 + tid>>3,
  // chunk = tid&7; swizzle key row&7 = (tid>>3)&7, invariant in j)
  const int srow_ = tid >> 3;
  const int es = srow_ & 7;
  const int scs = ((tid & 7) ^ es) << 3;            // swizzled chunk, shorts
  const long long gA0 = (long long)(m0 + srow_)       * lda + scs;
  const long long gA1 = (long long)(m0 + 64 + srow_)  * lda + scs;
  const long long gB0 = (long long)(n0 + srow_)       * ldb + scs;
  const long long gB1 = (long long)(n0 + 64 + srow_)  * ldb + scs;
  const long long gB2 = (long long)(n0 + 128 + srow_) * ldb + scs;
  const long long gB3 = (long long)(n0 + 192 + srow_) * ldb + scs;

  auto stageA = [&](int kt, int nb) {
    async16(A + gA0 + kt * 64, &As[nb * 8192 + tid * 8]);
    async16(A + gA1 + kt * 64, &As[nb * 8192 + 4096 + tid * 8]);
  };
  auto stageBlo = [&](int kt, int nb) {
    async16(Bt + gB0 + kt * 64, &Bs[nb * 16384 + tid * 8]);
    async16(Bt + gB1 + kt * 64, &Bs[nb * 16384 + 4096 + tid * 8]);
  };
  auto stageBhi = [&](int kt, int nb) {
    async16(Bt + gB2 + kt * 64, &Bs[nb * 16384 + 8192 + tid * 8]);
    async16(Bt + gB3 + kt * 64, &Bs[nb * 16384 + 12288 + tid * 8]);
  };

  f32x4 acc[4][4] = {};
  const int NT = K >> 6;

  stageA(0, 0); stageBlo(0, 0); stageBhi(0, 0);

  for (int t = 0; t < NT; ++t) {
    const int buf = t & 1, nb = buf ^ 1;

    // ---- phase 0: stage A(t+1)+Blo(t+1); wait tile t complete; MFMA nf 0,1
    if (t + 1 < NT) {
      stageA(t + 1, nb);
      stageBlo(t + 1, nb);
      asm volatile("s_waitcnt vmcnt(4)" ::: "memory");
    } else {
      asm volatile("s_waitcnt vmcnt(0)" ::: "memory");
    }
    __builtin_amdgcn_sched_barrier(0);
    __builtin_amdgcn_s_barrier();
    __builtin_amdgcn_sched_barrier(0);

    const unsigned short* Ab = &As[buf * 8192];
    const unsigned short* Bb = &Bs[buf * 16384];
    s16x8 a[4][2], b0[2][2];
#pragma unroll
    for (int mf = 0; mf < 4; ++mf)
#pragma unroll
      for (int ks = 0; ks < 2; ++ks)
        a[mf][ks] = *(const s16x8*)(Ab + (wr * 64 + mf * 16 + ml) * 64 +
                                    (((ks * 4 + quad) ^ e3) << 3));
#pragma unroll
    for (int nf = 0; nf < 2; ++nf)
#pragma unroll
      for (int ks = 0; ks < 2; ++ks)
        b0[nf][ks] = *(const s16x8*)(Bb + (wc * 64 + nf * 16 + ml) * 64 +
                                     (((ks * 4 + quad) ^ e3) << 3));
    __builtin_amdgcn_s_setprio(1);
#pragma unroll
    for (int mf = 0; mf < 4; ++mf)
#pragma unroll
      for (int nf = 0; nf < 2; ++nf) {
        acc[mf][nf] = __builtin_amdgcn_mfma_f32_16x16x32_bf16(a[mf][0], b0[nf][0], acc[mf][nf], 0, 0, 0);
        acc[mf][nf] = __builtin_amdgcn_mfma_f32_16x16x32_bf16(a[mf][1], b0[nf][1], acc[mf][nf], 0, 0, 0);
      }
    __builtin_amdgcn_s_setprio(0);
    __builtin_amdgcn_s_barrier();

    // ---- phase 1: stage Bhi(t+1); MFMA nf 2,3
    if (t + 1 < NT) stageBhi(t + 1, nb);
    s16x8 b1[2][2];
#pragma unroll
    for (int nf = 0; nf < 2; ++nf)
#pragma unroll
      for (int ks = 0; ks < 2; ++ks)
        b1[nf][ks] = *(const s16x8*)(Bb + (wc * 64 + (nf + 2) * 16 + ml) * 64 +
                                     (((ks * 4 + quad) ^ e3) << 3));
    __builtin_amdgcn_s_setprio(1);
#pragma unroll
    for (int mf = 0; mf < 4; ++mf)
#pragma unroll
      for (int nf = 0; nf < 2; ++nf) {
        acc[mf][nf + 2] = __builtin_amdgcn_mfma_f32_16x16x32_bf16(a[mf][0], b1[nf][0], acc[mf][nf + 2], 0, 0, 0);
        acc[mf][nf + 2] = __builtin_amdgcn_mfma_f32_16x16x32_bf16(a[mf][1], b1[nf][1], acc[mf][nf + 2], 0, 0, 0);
      }
    __builtin_amdgcn_s_setprio(0);
    // omega barrier: all waves' reads of buf done before next iter's stage
    // overwrites it. lgkm drain + fences per rule 18.
    asm volatile("s_waitcnt lgkmcnt(0)" ::: "memory");
    __builtin_amdgcn_sched_barrier(0);
    __builtin_amdgcn_s_barrier();
    __builtin_amdgcn_sched_barrier(0);
  }

#pragma unroll
  for (int mf = 0; mf < 4; ++mf)
#pragma unroll
    for (int nf = 0; nf < 4; ++nf)
#pragma unroll
      for (int r = 0; r < 4; ++r) {
        const int row = m0 + wr * 64 + mf * 16 + quad * 4 + r;
        const int col = n0 + wc * 64 + nf * 16 + ml;
        if (ODT)
          ((unsigned short*)Cv)[co + (long long)row * ldc + col] = f2bf(acc[mf][nf][r]);
        else
          ((float*)Cv)[co + (long long)row * ldc + col] = acc[mf][nf][r];
      }
}

// ---------------------------------------------------------------------------
// keys[:, :512] = rmsnorm(ckv[:,:512])*w ; keys[:,512:576] = rope(ckv[:,512:576])
// ---------------------------------------------------------------------------
__global__ __launch_bounds__(256) void kv_norm_rope(
    const float* __restrict__ ckv, const float* __restrict__ w,
    const int* __restrict__ pos_ids, unsigned short* __restrict__ keys)
{
  __shared__ float sbuf[4];
  const int r = blockIdx.x, tid = threadIdx.x;
  const float* row = ckv + (long long)r * 640;
  float x0 = row[tid], x1 = row[256 + tid];
  float ss = x0 * x0 + x1 * x1;
#pragma unroll
  for (int o = 32; o; o >>= 1) ss += __shfl_xor(ss, o);
  if ((tid & 63) == 0) sbuf[tid >> 6] = ss;
  __syncthreads();
  const float tot = sbuf[0] + sbuf[1] + sbuf[2] + sbuf[3];
  const float rms = rsqrtf(tot / 512.0f + 1e-6f);
  unsigned short* kr = keys + (long long)r * 576;
  kr[tid]       = f2bf(x0 * rms * w[tid]);
  kr[256 + tid] = f2bf(x1 * rms * w[256 + tid]);
  if (tid < 32) {
    const float pos = (float)pos_ids[r];
    const float invf = exp2f(-0.41524101186098287f * (float)tid); // 10000^(-tid/32)
    float sn, c; sincosf(pos * invf, &sn, &c);
    const float a0 = row[512 + 2 * tid], a1 = row[512 + 2 * tid + 1];
    kr[512 + tid] = f2bf(a0 * c - a1 * sn);
    kr[544 + tid] = f2bf(a1 * c + a0 * sn);
  }
}

__global__ __launch_bounds__(256) void q_norm(
    const float* __restrict__ qa_f32, const float* __restrict__ w,
    unsigned short* __restrict__ qa_bf)
{
  __shared__ float sbuf[4];
  const int r = blockIdx.x, tid = threadIdx.x;
  const float* row = qa_f32 + (long long)r * 1536;
  float x[6]; float ss = 0.f;
#pragma unroll
  for (int j = 0; j < 6; ++j) { x[j] = row[tid + 256 * j]; ss += x[j] * x[j]; }
#pragma unroll
  for (int o = 32; o; o >>= 1) ss += __shfl_xor(ss, o);
  if ((tid & 63) == 0) sbuf[tid >> 6] = ss;
  __syncthreads();
  const float tot = sbuf[0] + sbuf[1] + sbuf[2] + sbuf[3];
  const float rms = rsqrtf(tot / 1536.0f + 1e-6f);
#pragma unroll
  for (int j = 0; j < 6; ++j) {
    const int idx = tid + 256 * j;
    qa_bf[(long long)r * 1536 + idx] = f2bf(x[j] * rms * w[idx]);
  }
}

// rope q_pe [B,S,H*64] bf16 -> query[:, 512:576] bf16
__global__ __launch_bounds__(256) void rope_q(
    const unsigned short* __restrict__ qpe, const int* __restrict__ pos_ids,
    unsigned short* __restrict__ query)
{
  const int r = blockIdx.x;
  const int b = r >> 10, s = r & 1023;
  const float pos = (float)pos_ids[r];
  for (int p = threadIdx.x; p < 1024; p += 256) {
    const int h = p >> 5, i = p & 31;
    const float invf = exp2f(-0.41524101186098287f * (float)i);
    float sn, c; sincosf(pos * invf, &sn, &c);
    const float a0 = bf2f(qpe[(long long)r * 2048 + h * 64 + 2 * i]);
    const float a1 = bf2f(qpe[(long long)r * 2048 + h * 64 + 2 * i + 1]);
    const long long qrow = ((long long)(b * 32 + h) * 1024 + s) * 576;
    query[qrow + 512 + i] = f2bf(a0 * c - a1 * sn);
    query[qrow + 544 + i] = f2bf(a1 * c + a0 * sn);
  }
}

// keysT[b][d][t] = keys[b][t][d], d<512
__global__ __launch_bounds__(256) void transpose_keys(
    const unsigned short* __restrict__ keys, unsigned short* __restrict__ keysT)
{
  __shared__ unsigned short tile[32][36];
  const int tid = threadIdx.x;
  const int t0 = blockIdx.x * 32, d0 = blockIdx.y * 32, b = blockIdx.z;
  const int r = tid >> 3, c4 = (tid & 7) * 4;
  *(uint2*)(&tile[r][c4]) =
      *(const uint2*)(keys + ((long long)(b * 1024 + t0 + r) * 576 + d0 + c4));
  __syncthreads();
  unsigned short v[4];
#pragma unroll
  for (int j = 0; j < 4; ++j) v[j] = tile[c4 + j][r];
  *(uint2*)(keysT + ((long long)(b * 512 + d0 + r) * 1024 + t0 + c4)) = *(uint2*)v;
}

// ---------------------------------------------------------------------------
// MFMA flash attention (round-6 structure + T5 setprio).
// ---------------------------------------------------------------------------
__global__ __launch_bounds__(512, 2) void flash_mfma(
    const unsigned short* __restrict__ query,   // [64][1024][576]
    const unsigned short* __restrict__ keys,    // [2][1024][576]
    const unsigned short* __restrict__ keysT,   // [2][512][1024]
    unsigned short* __restrict__ ctx)           // [64][1024][512]
{
  __shared__ __align__(16) unsigned short Ks[2][32 * 640];  // 81920 B, swizzled
  __shared__ __align__(16) unsigned short Ps[2][8][640];    // 20480 B
  __shared__ float alpha_s[2][128];
  __shared__ float l_s[128];
  __shared__ __align__(16) int rflag[2][8];

  const int tid = threadIdx.x, w = tid >> 6, lane = tid & 63;
  const int quad = lane >> 4, ml = lane & 15;
  const int bid = blockIdx.x;
  const int bh = bid & 63;
  const int qt = 7 - (bid >> 6);          // heavy q-tiles first
  const int q0 = qt * 128;
  const int b = bh >> 5;
  const float scale = 0.07216878364870323f;

  const unsigned short* kb  = keys  + (long long)b * 1024 * 576;
  const unsigned short* vtb = keysT + (long long)b * 512 * 1024;

  const unsigned short* qg =
      query + ((long long)bh * 1024 + q0 + w * 16 + ml) * 576 + quad * 8;
  s16x8 qf[18];
#pragma unroll
  for (int ks = 0; ks < 18; ++ks) qf[ks] = *(const s16x8*)(qg + ks * 32);

  int koff[5];
#pragma unroll
  for (int j = 0; j < 5; ++j) {
    const int idx = tid + 512 * j;
    const int row = idx / 80;
    const int c16 = idx - row * 80;
    koff[j] = row * 576 + ((c16 ^ (row & 7)) << 3);   // shorts
  }
  char* ldsb = (char*)&Ks[0][0] + tid * 16;
  auto stage = [&](int t, int buf) {
    const long long toff = (long long)t * 18432;      // 32*576 shorts
    char* lb = ldsb + buf * 40960;
#pragma unroll
    for (int j = 0; j < 5; ++j)
      async16(kb + toff + koff[j], (unsigned short*)(lb + j * 8192));
  };

  const int e3 = ml & 7;                  // read-side swizzle key
  const int qi = q0 + w * 16 + ml;
  const int ntile = 4 * qt + 4;

  float m = -1e30f, l = 0.f;
  f32x4 o[8][4] = {};                     // [q-chunk][v-subtile]

  stage(0, 0);

  for (int ti = 0; ti < ntile; ++ti) {
    const int buf = ti & 1;
    const int t0 = ti * 32;

    if (ti + 1 < ntile) {
      stage(ti + 1, buf ^ 1);
      asm volatile("s_waitcnt vmcnt(5)" ::: "memory");
    } else {
      asm volatile("s_waitcnt vmcnt(0)" ::: "memory");
    }
    __builtin_amdgcn_sched_barrier(0);
    __builtin_amdgcn_s_barrier();         // alpha: Ks[buf] valid for all waves
    __builtin_amdgcn_sched_barrier(0);

    const bool wdead = (t0 > q0 + w * 16 + 15);   // whole wave above diagonal
    if (!wdead) {
      const unsigned short* Kb = &Ks[buf][0];
      f32x4 sc0 = {}, sc1 = {};
      __builtin_amdgcn_s_setprio(1);
#pragma unroll
      for (int ks = 0; ks < 18; ++ks) {
        const int xr = ((ks * 4 + quad) ^ e3) << 3;  // shorts within row
        s16x8 k0 = *(const s16x8*)(Kb + ml * 640 + xr);
        s16x8 k1 = *(const s16x8*)(Kb + (16 + ml) * 640 + xr);
        sc0 = __builtin_amdgcn_mfma_f32_16x16x32_bf16(k0, qf[ks], sc0, 0, 0, 0);
        sc1 = __builtin_amdgcn_mfma_f32_16x16x32_bf16(k1, qf[ks], sc1, 0, 0, 0);
      }
      __builtin_amdgcn_s_setprio(0);

      float p[8]; float mx = -1e30f;
      const bool tail = (t0 + 31 > q0 + w * 16);
#pragma unroll
      for (int r = 0; r < 4; ++r) {
        float v0 = sc0[r] * scale, v1 = sc1[r] * scale;
        if (tail) {
          if (t0 + quad * 4 + r > qi)      v0 = -1e30f;
          if (t0 + 16 + quad * 4 + r > qi) v1 = -1e30f;
        }
        p[r] = v0; p[4 + r] = v1;
        mx = fmaxf(mx, fmaxf(v0, v1));
      }
      mx = fmaxf(mx, __shfl_xor(mx, 16));
      mx = fmaxf(mx, __shfl_xor(mx, 32));

      float alpha = 1.0f;
      int resc = 0;
      if (!__all(mx - m <= 8.0f)) {       // defer-max: rescale only on growth>8
        const float mn = fmaxf(m, mx);
        alpha = __expf(m - mn);
        m = mn;
        l *= alpha;
        resc = 1;
      }
      if (lane == 0) rflag[buf][w] = resc;
      if (quad == 0) alpha_s[buf][w * 16 + ml] = alpha;

      float ps = 0.f;
#pragma unroll
      for (int j = 0; j < 8; ++j) { p[j] = __expf(p[j] - m); ps += p[j]; }
      ps += __shfl_xor(ps, 16);
      ps += __shfl_xor(ps, 32);
      l += ps;

#pragma unroll
      for (int c = 0; c < 2; ++c) {
        union { unsigned short u[4]; uint2 v; } pk;
        pk.u[0] = f2bf(p[c * 4 + 0]); pk.u[1] = f2bf(p[c * 4 + 1]);
        pk.u[2] = f2bf(p[c * 4 + 2]); pk.u[3] = f2bf(p[c * 4 + 3]);
        *(uint2*)(&Ps[buf][w][ml * 40 + c * 16 + quad * 4]) = pk.v;
      }
    } else {
      if (lane == 0) rflag[buf][w] = 0;
      if (quad == 0) alpha_s[buf][w * 16 + ml] = 1.0f;
    }

    // V fragments issued before the barrier so L2 latency hides under it
    const unsigned short* vg =
        vtb + (long long)(w * 64 + ml) * 1024 + t0 + quad * 8;
    s16x8 vf[4];
#pragma unroll
    for (int nt = 0; nt < 4; ++nt) vf[nt] = *(const s16x8*)(vg + nt * 16 * 1024);

    asm volatile("s_waitcnt lgkmcnt(0)" ::: "memory");
    __builtin_amdgcn_sched_barrier(0);
    __builtin_amdgcn_s_barrier();         // beta: Ps/alpha visible
    __builtin_amdgcn_sched_barrier(0);

    // ---- PV: wave owns v-dims [64w,64w+64) for all 128 q-rows ----
    const int4 ra = *(const int4*)&rflag[buf][0];
    const int4 rb = *(const int4*)&rflag[buf][4];
    if (ra.x | ra.y | ra.z | ra.w | rb.x | rb.y | rb.z | rb.w) {
#pragma unroll
      for (int qc = 0; qc < 8; ++qc)
#pragma unroll
        for (int r = 0; r < 4; ++r) {
          const float a = alpha_s[buf][qc * 16 + quad * 4 + r];
#pragma unroll
          for (int nt = 0; nt < 4; ++nt) o[qc][nt][r] *= a;
        }
    }

    __builtin_amdgcn_s_setprio(1);
#pragma unroll
    for (int qc = 0; qc < 8; ++qc) {
      if (t0 > q0 + qc * 16 + 15) continue;       // chunk above diagonal: P=0
      s16x8 pa = *(const s16x8*)(&Ps[buf][qc][ml * 40 + quad * 8]);
#pragma unroll
      for (int nt = 0; nt < 4; ++nt)
        o[qc][nt] = __builtin_amdgcn_mfma_f32_16x16x32_bf16(pa, vf[nt], o[qc][nt], 0, 0, 0);
    }
    __builtin_amdgcn_s_setprio(0);
  }

  // share row sums; normalize and store
  if (quad == 0) l_s[w * 16 + ml] = l;
  __syncthreads();

  unsigned short* cb = ctx + ((long long)bh * 1024 + q0) * 512 + w * 64 + ml;
#pragma unroll
  for (int qc = 0; qc < 8; ++qc)
#pragma unroll
    for (int r = 0; r < 4; ++r) {
      const float linv = 1.0f / l_s[qc * 16 + quad * 4 + r];
      unsigned short* crow = cb + (long long)(qc * 16 + quad * 4 + r) * 512;
#pragma unroll
      for (int nt = 0; nt < 4; ++nt)
        crow[nt * 16] = f2bf(o[qc][nt][r] * linv);
    }
}

// ---------------------------------------------------------------------------
extern "C" void kernel_launch(void* const* d_in, const int* in_sizes, int n_in,
                              void* d_out, int out_size, void* d_ws, size_t ws_size,
                              hipStream_t stream)
{
  (void)in_sizes; (void)n_in; (void)out_size; (void)ws_size;
  const float* hs      = (const float*)d_in[0];
  const int*   pos     = (const int*)d_in[2];
  const float* w_q_a   = (const float*)d_in[3];
  const float* q_a_ln  = (const float*)d_in[4];
  const float* q_rope  = (const float*)d_in[5];
  const float* fusedqk = (const float*)d_in[6];
  const float* w_kv_a  = (const float*)d_in[7];
  const float* kv_ln   = (const float*)d_in[8];
  const float* v_up    = (const float*)d_in[9];
  const float* w_o     = (const float*)d_in[10];
  char* ws = (char*)d_ws;

  // ---- overlaid workspace (peak 184,811,520 B; lifetimes verified) ----
  unsigned short* woT    = (unsigned short*)(ws + 0);           // [4096][4096] conv->s13
  unsigned short* vupT   = (unsigned short*)(ws + 33554432);    // 32x[128][512] conv->s12
  unsigned short* keys   = (unsigned short*)(ws + 37748736);    // [2048][576]  s4->s11
  unsigned short* keysT  = (unsigned short*)(ws + 40108032);    // [2][512][1024] s5->s11
  unsigned short* ctx    = (unsigned short*)(ws + 42205184);    // [64][1024][512] s11->s12
  unsigned short* fqkT   = (unsigned short*)(ws + 42205184);    //   32x[512][1536] conv->s10
  unsigned short* qab    = (unsigned short*)(ws + 92536832);    //   [2048][1536] s7->s10
  unsigned short* qpe    = (unsigned short*)(ws + 99828288);    //   [2048][2048] bf16 s8->s9
  unsigned short* hsb    = (unsigned short*)(ws + 92536832);    //   [2048][4096] conv->s6
  unsigned short* query  = (unsigned short*)(ws + 109314048);   // [64][1024][576] s9->s11
  unsigned short* wqT    = (unsigned short*)(ws + 109314048);   //   [1536][4096] conv->s6
  unsigned short* wkvT   = (unsigned short*)(ws + 121896960);   //   [640][4096] conv->s3
  unsigned short* qropeT = (unsigned short*)(ws + 127139840);   //   [2048][1536] conv->s8
  float*          ckv    = (float*)(ws + 133431296);            //   [2048][640] f32 s3->s4
  float*          qaf    = (float*)(ws + 138674176);            //   [2048][1536] f32 s6->s7
  unsigned short* outh   = (unsigned short*)(ws + 109314048);   // [2048][4096] s12->s13

  const dim3 blk(256);

  // conv/transpose pass (hsb overlaps nothing live; all weights -> bf16 [N][K])
  conv_bf16<<<dim3(4096), blk, 0, stream>>>(hs, hsb);                    // 2048*4096
  transpose_w<<<dim3(20, 128, 1), blk, 0, stream>>>(w_kv_a, wkvT, 4096, 576, 0, 0);
  transpose_w<<<dim3(48, 128, 1), blk, 0, stream>>>(w_q_a, wqT, 4096, 1536, 0, 0);
  transpose_w<<<dim3(64, 48, 1), blk, 0, stream>>>(q_rope, qropeT, 1536, 2048, 0, 0);
  transpose_w<<<dim3(16, 48, 32), blk, 0, stream>>>(fusedqk, fqkT, 1536, 512,
      (long long)1536 * 512, (long long)512 * 1536);
  transpose_w<<<dim3(4, 16, 32), blk, 0, stream>>>(v_up, vupT, 512, 128,
      (long long)512 * 128, (long long)128 * 512);
  transpose_w<<<dim3(128, 128, 1), blk, 0, stream>>>(w_o, woT, 4096, 4096, 0, 0);

  // s3: ckv[2048][640] = hsb @ wkvT^T   (N padded 576->640)
  gemm128<0><<<dim3(5, 16, 1), blk, 0, stream>>>(hsb, wkvT, (void*)ckv,
      4096, 4096, 4096, 640, 1, 0, 0, 0, 0, 0, 0);
  // s4: keys = [rmsnorm | rope]
  kv_norm_rope<<<dim3(2048), blk, 0, stream>>>(ckv, kv_ln, pos, keys);
  // s5: keysT
  transpose_keys<<<dim3(32, 16, 2), blk, 0, stream>>>(keys, keysT);
  // s6: qaf = hsb @ wqT^T
  gemm128<0><<<dim3(12, 16, 1), blk, 0, stream>>>(hsb, wqT, (void*)qaf,
      4096, 4096, 4096, 1536, 1, 0, 0, 0, 0, 0, 0);
  // s7: qab = rmsnorm(qaf)
  q_norm<<<dim3(2048), blk, 0, stream>>>(qaf, q_a_ln, qab);
  // s8: qpe = qab @ qropeT^T  (bf16 out)
  gemm128<1><<<dim3(16, 16, 1), blk, 0, stream>>>(qab, qropeT, (void*)qpe,
      1536, 1536, 1536, 2048, 1, 0, 0, 0, 0, 0, 0);
  // s9: query[:,512:576] = rope(qpe)
  rope_q<<<dim3(2048), blk, 0, stream>>>(qpe, pos, query);
  // s10: query[:,:512] = qab @ fqkT[h]^T   (gemm256: 2x8x64 = 1024 blocks)
  gemm256<1><<<dim3(2, 8, 64), dim3(512), 0, stream>>>(qab, fqkT, (void*)query,
      1536, 1536, 1536, 576, 32,
      (long long)1024 * 1536, 0, 0, (long long)512 * 1536,
      (long long)32 * 1024 * 576, (long long)1024 * 576);
  // s11: flash attention -> ctx  (128 q-rows/block, 8 q-tiles x 64 bh)
  flash_mfma<<<dim3(512), dim3(512), 0, stream>>>(query, keys, keysT, ctx);
  // s12: outh = ctx @ vupT[h]^T
  gemm128<1><<<dim3(1, 8, 64), blk, 0, stream>>>(ctx, vupT, (void*)outh,
      512, 512, 512, 4096, 32,
      (long long)32 * 1024 * 512, (long long)1024 * 512, 0, (long long)128 * 512,
      (long long)1024 * 4096, 128);
  // s13: out = outh @ woT^T  (f32 out, gemm256: 16x16 = 256 blocks)
  gemm256<0><<<dim3(16, 16, 1), dim3(512), 0, stream>>>(outh, woT, d_out,
      4096, 4096, 4096, 4096, 1, 0, 0, 0, 0, 0, 0);
}

// Round 5
// 904.853 us; speedup vs baseline: 1.1657x; 1.1657x over previous
//
#include <hip/hip_runtime.h>

// MLA forward. f32 in/out storage; internal bf16 MFMA, f32 accum.
// B=2 S=1024 H=32 HID=4096 QL=1536 KVL=512 ROPE=64 V=128 D=576
// Round 9: revert s10/s13 to gemm128 and flash to round-6 (no setprio) —
// both round-8 changes regressed. New: fuse s3+s6 into ONE gemm128 over
// concatenated B = [wqT;wkvT] [2176][4096] -> C f32 [2048][2176]
// (cols 0..1535 = qaf, 1536..2175 = ckv); grid 272 blocks fills the chip
// (was 80 + 192 sequential rounds).

typedef __attribute__((ext_vector_type(8))) short s16x8;
typedef __attribute__((ext_vector_type(4))) float f32x4;

__device__ __forceinline__ float bf2f(unsigned short u) {
  union { unsigned int i; float f; } v; v.i = ((unsigned int)u) << 16; return v.f;
}
__device__ __forceinline__ unsigned short f2bf(float f) {
  union { float f; unsigned int i; } v; v.f = f;
  unsigned int x = v.i;
  x += 0x7fffu + ((x >> 16) & 1u);   // RNE
  return (unsigned short)(x >> 16);
}

__device__ __forceinline__ void async16(const unsigned short* g, unsigned short* l) {
  __builtin_amdgcn_global_load_lds(
      (const __attribute__((address_space(1))) unsigned int*)g,
      (__attribute__((address_space(3))) unsigned int*)l, 16, 0, 0);
}

// ---------------------------------------------------------------------------
// f32 -> bf16 straight convert, 8 elems/thread, exact grid
// ---------------------------------------------------------------------------
__global__ __launch_bounds__(256) void conv_bf16(
    const float* __restrict__ s, unsigned short* __restrict__ d)
{
  const long long i = ((long long)blockIdx.x * 256 + threadIdx.x) * 8;
  float4 a = *(const float4*)(s + i);
  float4 b = *(const float4*)(s + i + 4);
  union { uint4 v; unsigned short u[8]; } o;
  o.u[0] = f2bf(a.x); o.u[1] = f2bf(a.y); o.u[2] = f2bf(a.z); o.u[3] = f2bf(a.w);
  o.u[4] = f2bf(b.x); o.u[5] = f2bf(b.y); o.u[6] = f2bf(b.z); o.u[7] = f2bf(b.w);
  *(uint4*)(d + i) = o.v;
}

// ---------------------------------------------------------------------------
// f32 [R][C] -> bf16 [Cp][R] transpose+convert. 32x32 tiles; tiles with
// c0 >= C write zeros (N padding). R%32==0, C%32==0, C%4==0.
// ---------------------------------------------------------------------------
__global__ __launch_bounds__(256) void transpose_w(
    const float* __restrict__ src, unsigned short* __restrict__ dst,
    int R, int C, long long sS, long long sD)
{
  __shared__ unsigned short tile[32][36];
  src += (long long)blockIdx.z * sS;
  dst += (long long)blockIdx.z * sD;
  const int c0 = blockIdx.x * 32, r0 = blockIdx.y * 32;
  const int tid = threadIdx.x;
  const int rr = tid >> 3, cc4 = (tid & 7) * 4;
  if (c0 < C) {
    float4 v = *(const float4*)(src + (long long)(r0 + rr) * C + c0 + cc4);
    tile[cc4 + 0][rr] = f2bf(v.x); tile[cc4 + 1][rr] = f2bf(v.y);
    tile[cc4 + 2][rr] = f2bf(v.z); tile[cc4 + 3][rr] = f2bf(v.w);
  } else {
#pragma unroll
    for (int j = 0; j < 4; ++j) tile[cc4 + j][rr] = 0;
  }
  __syncthreads();
  const int cr = tid >> 3, rc4 = (tid & 7) * 4;
  union { uint2 v; unsigned short u[4]; } o;
#pragma unroll
  for (int j = 0; j < 4; ++j) o.u[j] = tile[cr][rc4 + j];
  *(uint2*)(dst + (long long)(c0 + cr) * R + r0 + rc4) = o.v;
}

// ---------------------------------------------------------------------------
// m97-style GEMM: C[M,N] = A[M,K] * Bt[N,K]^T. A,Bt bf16 row-major.
// 128x128 block tile, BK=32, 4 waves each 64x64 (4x4 of mfma 16x16x32).
// Staging via global_load_lds width=16. M%128==0, (grid.x*128)<=N rows of Bt
// exist (N padded), K%32==0. ODT: 0=f32 C, 1=bf16 C.
// ---------------------------------------------------------------------------
template<int ODT>
__global__ __launch_bounds__(256) void gemm128(
    const unsigned short* __restrict__ A, const unsigned short* __restrict__ Bt,
    void* __restrict__ Cv, int K, int lda, int ldb, int ldc, int batH,
    long long sAb, long long sAh, long long sBb, long long sBh,
    long long sCb, long long sCh)
{
  const int z = blockIdx.z;
  const int bz = z / batH, hz = z % batH;
  A  += (long long)bz * sAb + (long long)hz * sAh;
  Bt += (long long)bz * sBb + (long long)hz * sBh;
  const long long co = (long long)bz * sCb + (long long)hz * sCh;

  __shared__ __align__(16) unsigned short As[128 * 32];
  __shared__ __align__(16) unsigned short Bs[128 * 32];

  const int tid = threadIdx.x, w = tid >> 6, lane = tid & 63;
  const int quad = lane >> 4, ml = lane & 15;
  const int wm = (w >> 1) * 64, wn = (w & 1) * 64;
  const int m0 = blockIdx.y * 128, n0 = blockIdx.x * 128;

  // staging: chunk c covers LDS bytes [16c,16c+16) = tile row c>>2, k8=(c&3)*8
  const int r0 = tid >> 2, k8 = (tid & 3) * 8;
  const unsigned short* Ag0 = A  + (long long)(m0 + r0)      * lda + k8;
  const unsigned short* Ag1 = A  + (long long)(m0 + r0 + 64) * lda + k8;
  const unsigned short* Bg0 = Bt + (long long)(n0 + r0)      * ldb + k8;
  const unsigned short* Bg1 = Bt + (long long)(n0 + r0 + 64) * ldb + k8;
  unsigned short* la0 = &As[tid * 8];
  unsigned short* la1 = &As[(tid + 256) * 8];
  unsigned short* lb0 = &Bs[tid * 8];
  unsigned short* lb1 = &Bs[(tid + 256) * 8];

  f32x4 acc[4][4] = {};

  for (int k0 = 0; k0 < K; k0 += 32) {
    __syncthreads();                  // LDS reads of prev iter done
    async16(Ag0 + k0, la0);
    async16(Ag1 + k0, la1);
    async16(Bg0 + k0, lb0);
    async16(Bg1 + k0, lb1);
    __syncthreads();                  // drains vmcnt before barrier

    s16x8 af[4], bf[4];
#pragma unroll
    for (int mi = 0; mi < 4; ++mi)
      af[mi] = *(const s16x8*)(&As[(wm + mi * 16 + ml) * 32 + quad * 8]);
#pragma unroll
    for (int ni = 0; ni < 4; ++ni)
      bf[ni] = *(const s16x8*)(&Bs[(wn + ni * 16 + ml) * 32 + quad * 8]);
#pragma unroll
    for (int mi = 0; mi < 4; ++mi)
#pragma unroll
      for (int ni = 0; ni < 4; ++ni)
        acc[mi][ni] = __builtin_amdgcn_mfma_f32_16x16x32_bf16(af[mi], bf[ni], acc[mi][ni], 0, 0, 0);
  }

#pragma unroll
  for (int mi = 0; mi < 4; ++mi)
#pragma unroll
    for (int ni = 0; ni < 4; ++ni)
#pragma unroll
      for (int r = 0; r < 4; ++r) {
        const int row = m0 + wm + mi * 16 + quad * 4 + r;
        const int col = n0 + wn + ni * 16 + ml;
        if (ODT)
          ((unsigned short*)Cv)[co + (long long)row * ldc + col] = f2bf(acc[mi][ni][r]);
        else
          ((float*)Cv)[co + (long long)row * ldc + col] = acc[mi][ni][r];
      }
}

// ---------------------------------------------------------------------------
// qckv row stride 2176: cols 0..1535 = q_a (f32), 1536..2111 = ckv (f32).
// keys[:, :512] = rmsnorm(ckv[:,:512])*w ; keys[:,512:576] = rope(ckv[:,512:])
// One block per row.
// ---------------------------------------------------------------------------
__global__ __launch_bounds__(256) void kv_norm_rope(
    const float* __restrict__ qckv, const float* __restrict__ w,
    const int* __restrict__ pos_ids, unsigned short* __restrict__ keys)
{
  __shared__ float sbuf[4];
  const int r = blockIdx.x, tid = threadIdx.x;
  const float* row = qckv + (long long)r * 2176 + 1536;
  float x0 = row[tid], x1 = row[256 + tid];
  float ss = x0 * x0 + x1 * x1;
#pragma unroll
  for (int o = 32; o; o >>= 1) ss += __shfl_xor(ss, o);
  if ((tid & 63) == 0) sbuf[tid >> 6] = ss;
  __syncthreads();
  const float tot = sbuf[0] + sbuf[1] + sbuf[2] + sbuf[3];
  const float rms = rsqrtf(tot / 512.0f + 1e-6f);
  unsigned short* kr = keys + (long long)r * 576;
  kr[tid]       = f2bf(x0 * rms * w[tid]);
  kr[256 + tid] = f2bf(x1 * rms * w[256 + tid]);
  if (tid < 32) {
    const float pos = (float)pos_ids[r];
    const float invf = exp2f(-0.41524101186098287f * (float)tid); // 10000^(-tid/32)
    float sn, c; sincosf(pos * invf, &sn, &c);
    const float a0 = row[512 + 2 * tid], a1 = row[512 + 2 * tid + 1];
    kr[512 + tid] = f2bf(a0 * c - a1 * sn);
    kr[544 + tid] = f2bf(a1 * c + a0 * sn);
  }
}

// qckv cols 0..1535 -> rmsnorm -> qab bf16 [2048][1536]
__global__ __launch_bounds__(256) void q_norm(
    const float* __restrict__ qckv, const float* __restrict__ w,
    unsigned short* __restrict__ qa_bf)
{
  __shared__ float sbuf[4];
  const int r = blockIdx.x, tid = threadIdx.x;
  const float* row = qckv + (long long)r * 2176;
  float x[6]; float ss = 0.f;
#pragma unroll
  for (int j = 0; j < 6; ++j) { x[j] = row[tid + 256 * j]; ss += x[j] * x[j]; }
#pragma unroll
  for (int o = 32; o; o >>= 1) ss += __shfl_xor(ss, o);
  if ((tid & 63) == 0) sbuf[tid >> 6] = ss;
  __syncthreads();
  const float tot = sbuf[0] + sbuf[1] + sbuf[2] + sbuf[3];
  const float rms = rsqrtf(tot / 1536.0f + 1e-6f);
#pragma unroll
  for (int j = 0; j < 6; ++j) {
    const int idx = tid + 256 * j;
    qa_bf[(long long)r * 1536 + idx] = f2bf(x[j] * rms * w[idx]);
  }
}

// rope q_pe [B,S,H*64] bf16 -> query[:, 512:576] bf16
__global__ __launch_bounds__(256) void rope_q(
    const unsigned short* __restrict__ qpe, const int* __restrict__ pos_ids,
    unsigned short* __restrict__ query)
{
  const int r = blockIdx.x;
  const int b = r >> 10, s = r & 1023;
  const float pos = (float)pos_ids[r];
  for (int p = threadIdx.x; p < 1024; p += 256) {
    const int h = p >> 5, i = p & 31;
    const float invf = exp2f(-0.41524101186098287f * (float)i);
    float sn, c; sincosf(pos * invf, &sn, &c);
    const float a0 = bf2f(qpe[(long long)r * 2048 + h * 64 + 2 * i]);
    const float a1 = bf2f(qpe[(long long)r * 2048 + h * 64 + 2 * i + 1]);
    const long long qrow = ((long long)(b * 32 + h) * 1024 + s) * 576;
    query[qrow + 512 + i] = f2bf(a0 * c - a1 * sn);
    query[qrow + 544 + i] = f2bf(a1 * c + a0 * sn);
  }
}

// keysT[b][d][t] = keys[b][t][d], d<512
__global__ __launch_bounds__(256) void transpose_keys(
    const unsigned short* __restrict__ keys, unsigned short* __restrict__ keysT)
{
  __shared__ unsigned short tile[32][36];
  const int tid = threadIdx.x;
  const int t0 = blockIdx.x * 32, d0 = blockIdx.y * 32, b = blockIdx.z;
  const int r = tid >> 3, c4 = (tid & 7) * 4;
  *(uint2*)(&tile[r][c4]) =
      *(const uint2*)(keys + ((long long)(b * 1024 + t0 + r) * 576 + d0 + c4));
  __syncthreads();
  unsigned short v[4];
#pragma unroll
  for (int j = 0; j < 4; ++j) v[j] = tile[c4 + j][r];
  *(uint2*)(keysT + ((long long)(b * 512 + d0 + r) * 1024 + t0 + c4)) = *(uint2*)v;
}

// ---------------------------------------------------------------------------
// MFMA flash attention. 8 waves / 512 threads, 128 q-rows per block.
// Wave w: QK+softmax for q-rows [16w,16w+16) (swapped mfma(K,Q), lane-local
// rows); PV for v-dims [64w,64w+64) over all 128 q-rows.
// K tile (32 keys x 576, rows padded to 1280B) double-buffered in LDS via
// global_load_lds; stage(t+1) issued at top of tile t, waited with counted
// vmcnt(5) + barrier at top of tile t+1 (full-tile flight, no vmcnt(0) drain
// in steady state). P/alpha/rflag double-buffered; 2 raw barriers per tile.
// ---------------------------------------------------------------------------
__global__ __launch_bounds__(512, 2) void flash_mfma(
    const unsigned short* __restrict__ query,   // [64][1024][576]
    const unsigned short* __restrict__ keys,    // [2][1024][576]
    const unsigned short* __restrict__ keysT,   // [2][512][1024]
    unsigned short* __restrict__ ctx)           // [64][1024][512]
{
  __shared__ __align__(16) unsigned short Ks[2][32 * 640];  // 81920 B, swizzled
  __shared__ __align__(16) unsigned short Ps[2][8][640];    // 20480 B
  __shared__ float alpha_s[2][128];
  __shared__ float l_s[128];
  __shared__ __align__(16) int rflag[2][8];

  const int tid = threadIdx.x, w = tid >> 6, lane = tid & 63;
  const int quad = lane >> 4, ml = lane & 15;
  const int bid = blockIdx.x;
  const int bh = bid & 63;
  const int qt = 7 - (bid >> 6);          // heavy q-tiles first
  const int q0 = qt * 128;
  const int b = bh >> 5;
  const float scale = 0.07216878364870323f;

  const unsigned short* kb  = keys  + (long long)b * 1024 * 576;
  const unsigned short* vtb = keysT + (long long)b * 512 * 1024;

  // Q fragments: wave w owns q-rows q0+16w..+16; lane (quad,ml) holds
  // Q[q0+16w+ml][32ks+8quad..+8] for ks=0..17 (B-operand layout).
  const unsigned short* qg =
      query + ((long long)bh * 1024 + q0 + w * 16 + ml) * 576 + quad * 8;
  s16x8 qf[18];
#pragma unroll
  for (int ks = 0; ks < 18; ++ks) qf[ks] = *(const s16x8*)(qg + ks * 32);

  // K staging: 2560 chunks of 16B (32 rows x 80 chunks; chunks 72-79 = pad,
  // never read). LDS linear dest; global source pre-swizzled c16^(row&7).
  int koff[5];
#pragma unroll
  for (int j = 0; j < 5; ++j) {
    const int idx = tid + 512 * j;
    const int row = idx / 80;
    const int c16 = idx - row * 80;
    koff[j] = row * 576 + ((c16 ^ (row & 7)) << 3);   // shorts
  }
  char* ldsb = (char*)&Ks[0][0] + tid * 16;
  auto stage = [&](int t, int buf) {
    const long long toff = (long long)t * 18432;      // 32*576 shorts
    char* lb = ldsb + buf * 40960;
#pragma unroll
    for (int j = 0; j < 5; ++j)
      async16(kb + toff + koff[j], (unsigned short*)(lb + j * 8192));
  };

  const int e3 = ml & 7;                  // read-side swizzle key
  const int qi = q0 + w * 16 + ml;
  const int ntile = 4 * qt + 4;

  float m = -1e30f, l = 0.f;
  f32x4 o[8][4] = {};                     // [q-chunk][v-subtile]

  stage(0, 0);

  for (int ti = 0; ti < ntile; ++ti) {
    const int buf = ti & 1;
    const int t0 = ti * 32;

    // issue next stage, then wait for current tile's data (+barrier => all
    // waves' loads landed). Counted vmcnt: only the 5 just-issued remain.
    if (ti + 1 < ntile) {
      stage(ti + 1, buf ^ 1);
      asm volatile("s_waitcnt vmcnt(5)" ::: "memory");
    } else {
      asm volatile("s_waitcnt vmcnt(0)" ::: "memory");
    }
    __builtin_amdgcn_sched_barrier(0);
    __builtin_amdgcn_s_barrier();         // alpha: Ks[buf] valid for all waves
    __builtin_amdgcn_sched_barrier(0);

    const bool wdead = (t0 > q0 + w * 16 + 15);   // whole wave above diagonal
    if (!wdead) {
      // ---- QK^T (swapped: A=K rows, B=Q) -> lane-local scores ----
      const unsigned short* Kb = &Ks[buf][0];
      f32x4 sc0 = {}, sc1 = {};
#pragma unroll
      for (int ks = 0; ks < 18; ++ks) {
        const int xr = ((ks * 4 + quad) ^ e3) << 3;  // shorts within row
        s16x8 k0 = *(const s16x8*)(Kb + ml * 640 + xr);
        s16x8 k1 = *(const s16x8*)(Kb + (16 + ml) * 640 + xr);
        sc0 = __builtin_amdgcn_mfma_f32_16x16x32_bf16(k0, qf[ks], sc0, 0, 0, 0);
        sc1 = __builtin_amdgcn_mfma_f32_16x16x32_bf16(k1, qf[ks], sc1, 0, 0, 0);
      }

      // scores: key = t0 + c*16 + quad*4 + r for q-row qi
      float p[8]; float mx = -1e30f;
      const bool tail = (t0 + 31 > q0 + w * 16);
#pragma unroll
      for (int r = 0; r < 4; ++r) {
        float v0 = sc0[r] * scale, v1 = sc1[r] * scale;
        if (tail) {
          if (t0 + quad * 4 + r > qi)      v0 = -1e30f;
          if (t0 + 16 + quad * 4 + r > qi) v1 = -1e30f;
        }
        p[r] = v0; p[4 + r] = v1;
        mx = fmaxf(mx, fmaxf(v0, v1));
      }
      mx = fmaxf(mx, __shfl_xor(mx, 16));
      mx = fmaxf(mx, __shfl_xor(mx, 32));

      float alpha = 1.0f;
      int resc = 0;
      if (!__all(mx - m <= 8.0f)) {       // defer-max: rescale only on growth>8
        const float mn = fmaxf(m, mx);
        alpha = __expf(m - mn);
        m = mn;
        l *= alpha;
        resc = 1;
      }
      if (lane == 0) rflag[buf][w] = resc;
      if (quad == 0) alpha_s[buf][w * 16 + ml] = alpha;

      float ps = 0.f;
#pragma unroll
      for (int j = 0; j < 8; ++j) { p[j] = __expf(p[j] - m); ps += p[j]; }
      ps += __shfl_xor(ps, 16);
      ps += __shfl_xor(ps, 32);
      l += ps;

#pragma unroll
      for (int c = 0; c < 2; ++c) {
        union { unsigned short u[4]; uint2 v; } pk;
        pk.u[0] = f2bf(p[c * 4 + 0]); pk.u[1] = f2bf(p[c * 4 + 1]);
        pk.u[2] = f2bf(p[c * 4 + 2]); pk.u[3] = f2bf(p[c * 4 + 3]);
        *(uint2*)(&Ps[buf][w][ml * 40 + c * 16 + quad * 4]) = pk.v;
      }
    } else {
      if (lane == 0) rflag[buf][w] = 0;
      if (quad == 0) alpha_s[buf][w * 16 + ml] = 1.0f;
    }

    // V fragments issued before the barrier so L2 latency hides under it
    const unsigned short* vg =
        vtb + (long long)(w * 64 + ml) * 1024 + t0 + quad * 8;
    s16x8 vf[4];
#pragma unroll
    for (int nt = 0; nt < 4; ++nt) vf[nt] = *(const s16x8*)(vg + nt * 16 * 1024);

    asm volatile("s_waitcnt lgkmcnt(0)" ::: "memory");
    __builtin_amdgcn_sched_barrier(0);
    __builtin_amdgcn_s_barrier();         // beta: Ps/alpha visible
    __builtin_amdgcn_sched_barrier(0);

    // ---- PV: wave owns v-dims [64w,64w+64) for all 128 q-rows ----
    const int4 ra = *(const int4*)&rflag[buf][0];
    const int4 rb = *(const int4*)&rflag[buf][4];
    if (ra.x | ra.y | ra.z | ra.w | rb.x | rb.y | rb.z | rb.w) {
#pragma unroll
      for (int qc = 0; qc < 8; ++qc)
#pragma unroll
        for (int r = 0; r < 4; ++r) {
          const float a = alpha_s[buf][qc * 16 + quad * 4 + r];
#pragma unroll
          for (int nt = 0; nt < 4; ++nt) o[qc][nt][r] *= a;
        }
    }

#pragma unroll
    for (int qc = 0; qc < 8; ++qc) {
      if (t0 > q0 + qc * 16 + 15) continue;       // chunk above diagonal: P=0
      s16x8 pa = *(const s16x8*)(&Ps[buf][qc][ml * 40 + quad * 8]);
#pragma unroll
      for (int nt = 0; nt < 4; ++nt)
        o[qc][nt] = __builtin_amdgcn_mfma_f32_16x16x32_bf16(pa, vf[nt], o[qc][nt], 0, 0, 0);
    }
  }

  // share row sums; normalize and store
  if (quad == 0) l_s[w * 16 + ml] = l;
  __syncthreads();

  unsigned short* cb = ctx + ((long long)bh * 1024 + q0) * 512 + w * 64 + ml;
#pragma unroll
  for (int qc = 0; qc < 8; ++qc)
#pragma unroll
    for (int r = 0; r < 4; ++r) {
      const float linv = 1.0f / l_s[qc * 16 + quad * 4 + r];
      unsigned short* crow = cb + (long long)(qc * 16 + quad * 4 + r) * 512;
#pragma unroll
      for (int nt = 0; nt < 4; ++nt)
        crow[nt * 16] = f2bf(o[qc][nt][r] * linv);
    }
}

// ---------------------------------------------------------------------------
extern "C" void kernel_launch(void* const* d_in, const int* in_sizes, int n_in,
                              void* d_out, int out_size, void* d_ws, size_t ws_size,
                              hipStream_t stream)
{
  (void)in_sizes; (void)n_in; (void)out_size; (void)ws_size;
  const float* hs      = (const float*)d_in[0];
  const int*   pos     = (const int*)d_in[2];
  const float* w_q_a   = (const float*)d_in[3];
  const float* q_a_ln  = (const float*)d_in[4];
  const float* q_rope  = (const float*)d_in[5];
  const float* fusedqk = (const float*)d_in[6];
  const float* w_kv_a  = (const float*)d_in[7];
  const float* kv_ln   = (const float*)d_in[8];
  const float* v_up    = (const float*)d_in[9];
  const float* w_o     = (const float*)d_in[10];
  char* ws = (char*)d_ws;

  // ---- overlaid workspace (peak 184,811,520 B; lifetimes verified) ----
  unsigned short* woT    = (unsigned short*)(ws + 0);           // [4096][4096] conv->s13
  unsigned short* vupT   = (unsigned short*)(ws + 33554432);    // 32x[128][512] conv->s12
  unsigned short* keys   = (unsigned short*)(ws + 37748736);    // [2048][576]  s4->s11
  unsigned short* keysT  = (unsigned short*)(ws + 40108032);    // [2][512][1024] s5->s11
  unsigned short* ctx    = (unsigned short*)(ws + 42205184);    // [64][1024][512] s11->s12
  unsigned short* fqkT   = (unsigned short*)(ws + 42205184);    //   32x[512][1536] conv->s10
  unsigned short* qab    = (unsigned short*)(ws + 92536832);    //   [2048][1536] s7->s10
  unsigned short* qpe    = (unsigned short*)(ws + 99828288);    //   [2048][2048] bf16 s8->s9
  unsigned short* hsb    = (unsigned short*)(ws + 92536832);    //   [2048][4096] conv->s36
  unsigned short* query  = (unsigned short*)(ws + 109314048);   // [64][1024][576] s9->s11
  unsigned short* wqkvT  = (unsigned short*)(ws + 109314048);   //   [2176][4096]: rows 0..1535 wq^T, 1536..2175 wkv^T; conv->s36
  unsigned short* qropeT = (unsigned short*)(ws + 127139840);   //   [2048][1536] conv->s8
  float*          qckv   = (float*)(ws + 133431296);            //   [2048][2176] f32 s36->s7 (cols 0..1535 qa, 1536.. ckv)
  unsigned short* outh   = (unsigned short*)(ws + 109314048);   // [2048][4096] s12->s13

  const dim3 blk(256);

  // conv/transpose pass (all weights -> bf16 [N][K])
  conv_bf16<<<dim3(4096), blk, 0, stream>>>(hs, hsb);                    // 2048*4096
  transpose_w<<<dim3(48, 128, 1), blk, 0, stream>>>(w_q_a, wqkvT, 4096, 1536, 0, 0);
  transpose_w<<<dim3(20, 128, 1), blk, 0, stream>>>(w_kv_a, wqkvT + (long long)1536 * 4096,
      4096, 576, 0, 0);
  transpose_w<<<dim3(64, 48, 1), blk, 0, stream>>>(q_rope, qropeT, 1536, 2048, 0, 0);
  transpose_w<<<dim3(16, 48, 32), blk, 0, stream>>>(fusedqk, fqkT, 1536, 512,
      (long long)1536 * 512, (long long)512 * 1536);
  transpose_w<<<dim3(4, 16, 32), blk, 0, stream>>>(v_up, vupT, 512, 128,
      (long long)512 * 128, (long long)128 * 512);
  transpose_w<<<dim3(128, 128, 1), blk, 0, stream>>>(w_o, woT, 4096, 4096, 0, 0);

  // s36 (fused s3+s6): qckv[2048][2176] = hsb @ wqkvT^T  (f32 out, 272 blocks)
  gemm128<0><<<dim3(17, 16, 1), blk, 0, stream>>>(hsb, wqkvT, (void*)qckv,
      4096, 4096, 4096, 2176, 1, 0, 0, 0, 0, 0, 0);
  // s4: keys = [rmsnorm | rope] from qckv cols 1536..
  kv_norm_rope<<<dim3(2048), blk, 0, stream>>>(qckv, kv_ln, pos, keys);
  // s5: keysT
  transpose_keys<<<dim3(32, 16, 2), blk, 0, stream>>>(keys, keysT);
  // s7: qab = rmsnorm(qckv cols 0..1535)
  q_norm<<<dim3(2048), blk, 0, stream>>>(qckv, q_a_ln, qab);
  // s8: qpe = qab @ qropeT^T  (bf16 out)
  gemm128<1><<<dim3(16, 16, 1), blk, 0, stream>>>(qab, qropeT, (void*)qpe,
      1536, 1536, 1536, 2048, 1, 0, 0, 0, 0, 0, 0);
  // s9: query[:,512:576] = rope(qpe)
  rope_q<<<dim3(2048), blk, 0, stream>>>(qpe, pos, query);
  // s10: query[:,:512] = qab @ fqkT[h]^T
  gemm128<1><<<dim3(4, 8, 64), blk, 0, stream>>>(qab, fqkT, (void*)query,
      1536, 1536, 1536, 576, 32,
      (long long)1024 * 1536, 0, 0, (long long)512 * 1536,
      (long long)32 * 1024 * 576, (long long)1024 * 576);
  // s11: flash attention -> ctx  (128 q-rows/block, 8 q-tiles x 64 bh)
  flash_mfma<<<dim3(512), dim3(512), 0, stream>>>(query, keys, keysT, ctx);
  // s12: outh = ctx @ vupT[h]^T
  gemm128<1><<<dim3(1, 8, 64), blk, 0, stream>>>(ctx, vupT, (void*)outh,
      512, 512, 512, 4096, 32,
      (long long)32 * 1024 * 512, (long long)1024 * 512, 0, (long long)128 * 512,
      (long long)1024 * 4096, 128);
  // s13: out = outh @ woT^T  (f32 out)
  gemm128<0><<<dim3(32, 16, 1), blk, 0, stream>>>(outh, woT, d_out,
      4096, 4096, 4096, 4096, 1, 0, 0, 0, 0, 0, 0);
}